// Round 13
// baseline (626.389 us; speedup 1.0000x reference)
//
#include <hip/hip_runtime.h>

#define NN 40000
#define NE 320000
#define C 256
#define KORD 5
#define KT 1280          // fused K = 5 * 256
#define ELLW 40          // ELL width: max Poisson(8) degree over 40k rows ~30

#define PBLK 512         // persistent grid: 512 blocks x 1024 thr = 2 blocks/CU exact
#define PTHR 1024
#define PWAVES (PBLK * (PTHR / 64))   // 8192 waves

typedef __attribute__((ext_vector_type(8))) short short8;   // 8 x bf16 (4 VGPR)
typedef __attribute__((ext_vector_type(4))) float floatx4;  // 4 x f32
typedef unsigned short bf16_t;
typedef unsigned long long u64;

__device__ __forceinline__ bf16_t f2bf(float f) {
    union { float f; unsigned u; } v; v.f = f;
    unsigned r = v.u + 0x7fffu + ((v.u >> 16) & 1u);  // RTNE
    return (bf16_t)(r >> 16);
}
__device__ __forceinline__ float bf2f(bf16_t h) {
    union { unsigned u; float f; } v; v.u = ((unsigned)h) << 16;
    return v.f;
}

#define GLL16(gsrc, ldst)                                                        \
    __builtin_amdgcn_global_load_lds(                                            \
        (const __attribute__((address_space(1))) void*)(gsrc),                   \
        (__attribute__((address_space(3))) void*)(ldst), 16, 0, 0)

// ---------------- mega0: count (1250 blocks) + convx (10000) + wt (1280) ----------------
__global__ __launch_bounds__(256)
void mega0_kernel(const int* __restrict__ ei,
                  int* __restrict__ self, int* __restrict__ cntA,
                  const float* __restrict__ x, bf16_t* __restrict__ abf,
                  const float* __restrict__ W, bf16_t* __restrict__ WT) {
    int bid = blockIdx.x, t = threadIdx.x;
    if (bid < 1250) {                    // count: 1250*256 = NE exact
        int e = bid * 256 + t;
        int r = ei[e];
        int c = ei[NE + e];
        atomicAdd(&cntA[r], 1);
        if (r == c) atomicAdd(&self[r], 1);        // ~8 edges total
    } else if (bid < 11250) {            // convx: 10000*256 = NN*64 exact
        int i = (bid - 1250) * 256 + t;
        int n = i >> 6, cg = i & 63;
        float4 f = *(const float4*)&x[(size_t)n * C + cg * 4];
        ushort4 h;
        h.x = f2bf(f.x); h.y = f2bf(f.y); h.z = f2bf(f.z); h.w = f2bf(f.w);
        *(ushort4*)&abf[(size_t)n * KT + cg * 4] = h;
    } else {                             // wt: 1280*256 = 256*KT exact
        int i = (bid - 11250) * 256 + t;
        int n = i & 255, kt = i >> 8;
        WT[(size_t)n * KT + kt] = f2bf(W[(size_t)kt * 256 + n]);
    }
}

// ---------------- software grid barrier (device-scope, graph-capture-safe) ----------------
// Sense-reversing: gen at bar[0], arrival counter at bar[32] (128 B apart).
// Release (ACQ_REL add) flushes writer-XCD L2; ACQUIRE spin invalidates reader
// caches -> plain stores from phase k visible to phase k+1 across XCDs (G16).
// Co-residency: PBLK=512 = 2 blocks/CU exact (launch_bounds caps VGPR<=64, LDS 0).
__device__ __forceinline__ void grid_sync(unsigned* bar) {
    __syncthreads();
    if (threadIdx.x == 0) {
        unsigned g = __hip_atomic_load(&bar[0], __ATOMIC_ACQUIRE, __HIP_MEMORY_SCOPE_AGENT);
        unsigned a = __hip_atomic_fetch_add(&bar[32], 1u, __ATOMIC_ACQ_REL, __HIP_MEMORY_SCOPE_AGENT);
        if (a == PBLK - 1) {
            __hip_atomic_store(&bar[32], 0u, __ATOMIC_RELAXED, __HIP_MEMORY_SCOPE_AGENT);
            __hip_atomic_store(&bar[0], g + 1u, __ATOMIC_RELEASE, __HIP_MEMORY_SCOPE_AGENT);
        } else {
            while (__hip_atomic_load(&bar[0], __ATOMIC_ACQUIRE, __HIP_MEMORY_SCOPE_AGENT) == g)
                __builtin_amdgcn_s_sleep(2);
        }
    }
    __syncthreads();
}

// one ELL spmm row (r10-verified math; FP order j-ascending in cursor order)
__device__ __forceinline__ void spmm_row(const bf16_t* __restrict__ Vb,
                                         const bf16_t* __restrict__ subb,
                                         const int* __restrict__ cntA,
                                         const u64* __restrict__ ell,
                                         bf16_t* __restrict__ outb,
                                         int n, int lane, float alpha, int use_sub) {
    const u64* row = ell + (size_t)n * ELLW;
    int jmax = (cntA[n] + 7) & ~7;          // wave-uniform, <= ELLW
    int cb = lane * 4;
    float a0 = 0.f, a1 = 0.f, a2 = 0.f, a3 = 0.f;
    for (int j = 0; j < jmax; j += 8) {
        u64 pp[8]; ushort4 vv[8];
#pragma unroll
        for (int u = 0; u < 8; ++u) pp[u] = row[j + u];
#pragma unroll
        for (int u = 0; u < 8; ++u)
            vv[u] = *(const ushort4*)&Vb[(size_t)(unsigned)(pp[u] & 0xffffffffu) * KT + cb];
#pragma unroll
        for (int u = 0; u < 8; ++u) {
            union { unsigned u; float f; } wb; wb.u = (unsigned)(pp[u] >> 32);
            float w = wb.f;
            a0 += w * bf2f(vv[u].x); a1 += w * bf2f(vv[u].y);
            a2 += w * bf2f(vv[u].z); a3 += w * bf2f(vv[u].w);
        }
    }
    float r0, r1, r2, r3;
    if (use_sub) {
        ushort4 s = *(const ushort4*)&subb[(size_t)n * KT + cb];
        r0 = alpha * a0 - bf2f(s.x);
        r1 = alpha * a1 - bf2f(s.y);
        r2 = alpha * a2 - bf2f(s.z);
        r3 = alpha * a3 - bf2f(s.w);
    } else {
        r0 = alpha * a0; r1 = alpha * a1; r2 = alpha * a2; r3 = alpha * a3;
    }
    ushort4 h;
    h.x = f2bf(r0); h.y = f2bf(r1); h.z = f2bf(r2); h.w = f2bf(r3);
    *(ushort4*)&outb[(size_t)n * KT + cb] = h;
}

// ---------------- persistent: ELL fill + 4 Chebyshev passes, 5 grid barriers ----------------
// Replaces 5 dispatches (fill + 4 spmm) with one -> 4 launch gaps removed
// (~4-5 us each, r9-validated); barrier cost ~1 us x 5 (512 atomics each).
// spmm floor per pass unchanged: 164 MB gathers at ~4 TB/s fabric rate.
__global__ __launch_bounds__(PTHR, 8)
void spmm4p_kernel(const int* __restrict__ ei,
                   const float* __restrict__ ew,
                   const int* __restrict__ self,
                   const int* __restrict__ cntA,
                   int* __restrict__ cur,
                   u64* __restrict__ ell,
                   bf16_t* __restrict__ abf,
                   unsigned* __restrict__ bar) {
    // phase 0: ELL fill (dis on the fly; pads stay zeroed by host memset)
    {
        int e = blockIdx.x * PTHR + threadIdx.x;    // stride 524288 > NE -> single iter
        if (e < NE) {
            int r = ei[e];
            int c = ei[NE + e];
            int pos = atomicAdd(&cur[r], 1);
            float w = (r != c) ? ew[e] : 0.0f;
            int dgr = cntA[r] - self[r];
            int dgc = cntA[c] - self[c];
            float dr = (dgr > 0) ? rsqrtf((float)dgr) : 0.0f;
            float dc = (dgc > 0) ? rsqrtf((float)dgc) : 0.0f;
            float v = -dr * w * dc;
            union { float f; unsigned u; } vb; vb.f = v;
            ell[(size_t)r * ELLW + pos] = ((u64)vb.u << 32) | (unsigned)c;
        }
    }
    grid_sync(bar);

    int lane = threadIdx.x & 63;
    int gw = blockIdx.x * (PTHR / 64) + (threadIdx.x >> 6);   // 0..8191

    // pass 1: T1 = L x
    for (int n = gw; n < NN; n += PWAVES)
        spmm_row(abf + 0 * 256, nullptr, cntA, ell, abf + 1 * 256, n, lane, 1.0f, 0);
    grid_sync(bar);
    // pass 2: T2 = 2 L T1 - T0
    for (int n = gw; n < NN; n += PWAVES)
        spmm_row(abf + 1 * 256, abf + 0 * 256, cntA, ell, abf + 2 * 256, n, lane, 2.0f, 1);
    grid_sync(bar);
    // pass 3: T3 = 2 L T2 - T1
    for (int n = gw; n < NN; n += PWAVES)
        spmm_row(abf + 2 * 256, abf + 1 * 256, cntA, ell, abf + 3 * 256, n, lane, 2.0f, 1);
    grid_sync(bar);
    // pass 4: T4 = 2 L T3 - T2
    for (int n = gw; n < NN; n += PWAVES)
        spmm_row(abf + 3 * 256, abf + 2 * 256, cntA, ell, abf + 4 * 256, n, lane, 2.0f, 1);
}

// ---------------- fused bf16 MFMA GEMM (3-buffer, counted-vmcnt; at byte floor) ----------------
// out[M=40000][256] = Abf[M][1280] @ WT^T + bias.  (r1/r7 form, measured 44.0-45.4)
// CONCLUSION r0-r11: every schedule/tile/layout variant lands at 44-46 us =
// 143 MB mixed HBM traffic at ~3.3 TB/s. Frozen.
__global__ __launch_bounds__(256, 2)
void gemm_mfma(const bf16_t* __restrict__ Abf,  // [NN][KT]
               const bf16_t* __restrict__ WT,   // [256][KT]
               const float* __restrict__ bias,
               float* __restrict__ out) {
    __shared__ bf16_t smem[3][12288];  // per buf: As = [0,4096), Bs = [4096,12288)
    int tid = threadIdx.x;
    int w = tid >> 6, lane = tid & 63;
    int m0 = blockIdx.x * 64;
    int n0 = blockIdx.y * 128;
    int wm = w & 1, wn = w >> 1;
    int quad = lane >> 4, l16 = lane & 15, l7 = l16 & 7;

    const bf16_t* srcbase[6];
#pragma unroll
    for (int j = 0; j < 6; ++j) {
        int gi = (w * 6 + j) * 64 + lane;           // 0..1535
        int isB = gi >= 512;
        int t  = isB ? gi - 512 : gi;
        int row = t >> 3;                           // A: 0..63, B: 0..127
        int pg = t & 7;
        int g  = pg ^ (row & 7);                    // physical k-granule slot
        srcbase[j] = (isB ? WT + (size_t)(n0 + row) * KT
                          : Abf + (size_t)(m0 + row) * KT) + g * 8;
    }

    int arowb = wm * 32 + l16;    // A fragment base row (mt adds 16)
    int browb = wn * 64 + l16;    // B fragment base row (nt adds 16)

    floatx4 acc[2][4] = {};

    const int NT = KT / 64;       // 20

    // prologue: issue tiles 0 and 1 (12 loads/wave outstanding)
#pragma unroll
    for (int j = 0; j < 6; ++j)
        GLL16(srcbase[j] + 0 * 64, &smem[0][(w * 6 + j) * 512]);
#pragma unroll
    for (int j = 0; j < 6; ++j)
        GLL16(srcbase[j] + 1 * 64, &smem[1][(w * 6 + j) * 512]);

    int bufc = 0;                 // buffer holding tile t
    for (int t = 0; t < NT; ++t) {
        if (t < NT - 1) {
            asm volatile("s_waitcnt vmcnt(6)" ::: "memory");
        } else {
            asm volatile("s_waitcnt vmcnt(0)" ::: "memory");
        }
        __builtin_amdgcn_sched_barrier(0);
        __builtin_amdgcn_s_barrier();   // all waves: tile t landed; buf[(t-1)%3] reads done

        if (t + 2 < NT) {
            int bnext = bufc + 2; if (bnext >= 3) bnext -= 3;
#pragma unroll
            for (int j = 0; j < 6; ++j)
                GLL16(srcbase[j] + (t + 2) * 64, &smem[bnext][(w * 6 + j) * 512]);
        }

        const bf16_t* sb = smem[bufc];
#pragma unroll
        for (int c = 0; c < 2; ++c) {              // two 32-k chunks inside BK=64
            int gp   = (c * 4 + quad) ^ l7;        // physical granule for this frag
            int aoff = (arowb * 8 + gp) * 8;
            int boff = 4096 + (browb * 8 + gp) * 8;
            short8 af[2], bfr[4];
#pragma unroll
            for (int mt = 0; mt < 2; ++mt) af[mt]  = *(const short8*)&sb[aoff + mt * 1024];
#pragma unroll
            for (int nt = 0; nt < 4; ++nt) bfr[nt] = *(const short8*)&sb[boff + nt * 1024];
#pragma unroll
            for (int mt = 0; mt < 2; ++mt)
#pragma unroll
                for (int nt = 0; nt < 4; ++nt)
                    acc[mt][nt] = __builtin_amdgcn_mfma_f32_16x16x32_bf16(
                        af[mt], bfr[nt], acc[mt][nt], 0, 0, 0);
        }

        bufc += 1; if (bufc == 3) bufc = 0;
    }

    // epilogue: C/D layout col=lane&15, row=quad*4+reg  (m89-verified)
#pragma unroll
    for (int nt = 0; nt < 4; ++nt) {
        int n = n0 + wn * 64 + nt * 16 + l16;
        float bv = bias[n];
#pragma unroll
        for (int mt = 0; mt < 2; ++mt) {
            int mbase = m0 + wm * 32 + mt * 16 + quad * 4;
#pragma unroll
            for (int r = 0; r < 4; ++r)
                out[(size_t)(mbase + r) * C + n] = acc[mt][nt][r] + bv;
        }
    }
}

// ---------------- launch ----------------

extern "C" void kernel_launch(void* const* d_in, const int* in_sizes, int n_in,
                              void* d_out, int out_size, void* d_ws, size_t ws_size,
                              hipStream_t stream) {
    const float* x    = (const float*)d_in[0];
    const int*   ei   = (const int*)d_in[1];
    const float* ew   = (const float*)d_in[2];
    const float* W    = (const float*)d_in[3];   // [5][256][256]
    const float* bias = (const float*)d_in[4];
    float* out = (float*)d_out;

    char* p = (char*)d_ws;
    auto carve = [&](size_t bytes) {
        char* q = p;
        p += (bytes + 255) & ~(size_t)255;
        return q;
    };
    // self, cntA, cur, bar, ell contiguous -> ONE memset covers all five.
    int*      self = (int*)     carve(NN * 4);
    int*      cntA = (int*)     carve(NN * 4);
    int*      cur  = (int*)     carve(NN * 4);
    unsigned* bar  = (unsigned*)carve(256);                    // gen @0, counter @128
    u64*      ell  = (u64*)     carve((size_t)NN * ELLW * 8);  // 12.8 MB, zero-padded
    bf16_t*   abf  = (bf16_t*)  carve((size_t)NN * KT * 2);    // bf16 recursion state
    bf16_t*   WT   = (bf16_t*)  carve((size_t)C * KT * 2);     // W transposed bf16
    (void)ws_size; (void)n_in; (void)in_sizes; (void)out_size;

    // one memset: self + cntA + cur + bar + ell (contiguous carves)
    hipMemsetAsync(self, 0, (size_t)NN * 4 * 3 + 256 + (size_t)NN * ELLW * 8, stream);

    // count + convx + wt in one launch (block-range partitioned)
    mega0_kernel<<<12530, 256, 0, stream>>>(ei, self, cntA, x, abf, W, WT);

    // fill + 4 Chebyshev passes in ONE persistent kernel (software grid barriers)
    spmm4p_kernel<<<PBLK, PTHR, 0, stream>>>(ei, ew, self, cntA, cur, ell, abf, bar);

    // fused GEMM: out = abf @ WT^T + bias
    dim3 ggrid(625, 2);
    gemm_mfma<<<ggrid, 256, 0, stream>>>(abf, WT, bias, out);
}